// Round 4
// baseline (134.377 us; speedup 1.0000x reference)
//
#include <hip/hip_runtime.h>
#include <math.h>
#include <cstddef>

// Shapes fixed by setup_inputs()
#define B_  16
#define T2_ 2048
#define T1_ 512
#define F_  128

constexpr float DELTA_C  = 10.0f;
constexpr float EPS_C    = 1e-8f;
constexpr float THRESH_C = 0.9f;
constexpr float STEEP_C  = 10.0f;

typedef float f4v __attribute__((ext_vector_type(4)));

// --- K1 (fused): activity + imv_proposal, one wave per (b,t).
// alpha streamed once -> nontemporal; writes a single float2 {prop, act}.
__global__ __launch_bounds__(256) void actprop_kernel(const float* __restrict__ mels,
                                                      const float* __restrict__ alpha,
                                                      const int* __restrict__ mel_mask,
                                                      float2* __restrict__ pa) {
    int wid  = (int)((blockIdx.x * blockDim.x + threadIdx.x) >> 6);
    int lane = threadIdx.x & 63;
    if (wid >= B_ * T2_) return;
    int t = wid % T2_;

    const f4v* row = (const f4v*)(alpha + (size_t)wid * T1_);
    f4v v0 = __builtin_nontemporal_load(&row[lane]);        // first 1 KiB, coalesced
    f4v v1 = __builtin_nontemporal_load(&row[lane + 64]);   // second 1 KiB

    float d = 0.f, n0 = 0.f, n1 = 0.f;
    if (t > 0) {
        float2 x = ((const float2*)(mels + (size_t)(wid - 1) * F_))[lane];
        float2 y = ((const float2*)(mels + (size_t)wid * F_))[lane];
        d  = x.x * y.x + x.y * y.y;
        n0 = x.x * x.x + x.y * x.y;
        n1 = y.x * y.x + y.y * y.y;
    }

    float fL = (float)(lane * 4);
    float psum = v0.x * fL + v0.y * (fL + 1.f) + v0.z * (fL + 2.f) + v0.w * (fL + 3.f)
               + v1.x * (fL + 256.f) + v1.y * (fL + 257.f) + v1.z * (fL + 258.f) + v1.w * (fL + 259.f);

    for (int off = 32; off > 0; off >>= 1) {
        psum += __shfl_xor(psum, off, 64);
        d    += __shfl_xor(d,    off, 64);
        n0   += __shfl_xor(n0,   off, 64);
        n1   += __shfl_xor(n1,   off, 64);
    }

    if (lane == 0) {
        float a_val;
        if (t == 0) {
            a_val = 1.0f;
        } else {
            float cs = d / (fmaxf(sqrtf(n0), 1e-12f) * fmaxf(sqrtf(n1), 1e-12f));
            a_val = 1.0f / (1.0f + __expf(-STEEP_C * (THRESH_C - cs)));
        }
        float2 o = {psum, a_val * (float)mel_mask[wid]};
        pa[wid] = o;
    }
}

// --- K2 (fused scan+pool): 64 blocks per batch; each block redundantly
// recomputes the batch scan (cheap, L2-hot), builds {key, 1/Z} in LDS,
// then pools 8 phonemes (2 per wave) straight out of LDS.
__global__ __launch_bounds__(256) void pool_kernel(const float* __restrict__ mels,
                                                   const float2* __restrict__ pa,
                                                   const int* __restrict__ mel_mask,
                                                   const int* __restrict__ text_mask,
                                                   float* __restrict__ imv_out,
                                                   float* __restrict__ aligned,
                                                   float* __restrict__ dur) {
    int bi   = blockIdx.x;             // 0..1023
    int b    = bi >> 6, sblk = bi & 63;
    int tid  = threadIdx.x;
    int wave = tid >> 6, lane = tid & 63;

    __shared__ float s_key[T2_];
    __shared__ float s_r[T2_];
    __shared__ float s_wsum[4];
    __shared__ int   s_am4[4], s_tm4[4];
    __shared__ int   s_tm[T1_];

    const float2* pr = pa + (size_t)b * T2_;
    const int*    mm = mel_mask  + (size_t)b * T2_;
    const int*    tm = text_mask + (size_t)b * T1_;

    int tmv0 = tm[tid], tmv1 = tm[tid + 256];
    s_tm[tid] = tmv0; s_tm[tid + 256] = tmv1;

    // --- scan phase (redundant per block) ---
    float e[8];
    int   mmv[8];
    int t0 = tid * 8;
    float prev = (t0 > 0) ? pr[t0 - 1].x : 0.0f;
    float run = 0.0f;
    int am_local = 0;
    for (int i = 0; i < 8; i++) {
        int t = t0 + i;
        float2 cur = pr[t];
        float d = (t == 0) ? 0.0f : (cur.x - prev) * cur.y;
        prev = cur.x;
        d = fminf(fmaxf(d, 0.0f), 1.0f);
        run += d;
        e[i] = run;
        mmv[i] = mm[t];
        am_local += mmv[i];
    }
    int tm_local = tmv0 + tmv1;
    for (int off = 32; off > 0; off >>= 1) {
        am_local += __shfl_xor(am_local, off, 64);
        tm_local += __shfl_xor(tm_local, off, 64);
    }
    if (lane == 0) { s_am4[wave] = am_local; s_tm4[wave] = tm_local; }

    float v = run;                               // wave inclusive scan
    for (int off = 1; off < 64; off <<= 1) {
        float u = __shfl_up(v, off, 64);
        if (lane >= off) v += u;
    }
    if (lane == 63) s_wsum[wave] = v;
    __syncthreads();                             // B1

    float woff = 0.0f;
    for (int w = 0; w < 4; w++) woff += (w < wave) ? s_wsum[w] : 0.0f;
    float excl = woff + v - run;
    for (int i = 0; i < 8; i++) {
        int t = t0 + i;
        s_key[t] = (e[i] + excl) * (float)mmv[i];   // pre-scale imv, temp storage
    }
    __syncthreads();                             // B2

    int am_total = s_am4[0] + s_am4[1] + s_am4[2] + s_am4[3];
    int tm_total = s_tm4[0] + s_tm4[1] + s_tm4[2] + s_tm4[3];
    int last_idx = max(am_total - 1, 0);
    float last_val = fmaxf(s_key[last_idx], 1e-6f);
    float scale = fmaxf((float)tm_total - 1.0f, 0.0f) / last_val;
    __syncthreads();                             // B3 (all read last_val before overwrite)

    for (int i = 0; i < 8; i++) {
        int t = t0 + i;
        int valid = mmv[i];
        float vv = s_key[t] * scale * (float)valid;
        if (sblk == 0) imv_out[(size_t)b * T2_ + t] = vv;
        // softmax denominator: 6-term band; excluded terms < 1e-39 (flush to 0)
        int c = (int)floorf(vv);
        float Z = 0.0f;
        for (int s = c - 2; s <= c + 3; s++) {
            if (s >= 0 && s < T1_ && s_tm[s]) {
                float dd = vv - (float)s;
                Z += __expf(-DELTA_C * dd * dd);
            }
        }
        Z = fmaxf(Z, 1e-30f);
        s_key[t] = valid ? vv : 3.0e4f;          // monotone search key
        s_r[t]   = valid ? (1.0f / Z) : 0.0f;    // r = am/Z
    }
    __syncthreads();                             // B4

    // --- pool phase: 2 adjacent phonemes per wave ---
    int s0 = sblk * 8 + wave * 2;
    float fs0 = (float)s0, fs1 = fs0 + 1.0f;
    const float2* mel2 = (const float2*)(mels + (size_t)b * T2_ * F_);

    float lov = fs0 - 3.0f, hiv = fs1 + 3.0f;
    int lo = 0, hi = T2_;
    while (lo < hi) { int mid = (lo + hi) >> 1; if (s_key[mid] >= lov) hi = mid; else lo = mid + 1; }
    int t_lo = lo;
    hi = T2_;
    while (lo < hi) { int mid = (lo + hi) >> 1; if (s_key[mid] > hiv) hi = mid; else lo = mid + 1; }
    int t_hi = lo;

    float ax0 = 0.f, ay0 = 0.f, g0s = 0.f;
    float ax1 = 0.f, ay1 = 0.f, g1s = 0.f;
    int t = t_lo;
    for (; t + 2 <= t_hi; t += 2) {
        float k0 = s_key[t], r0 = s_r[t];
        float k1 = s_key[t + 1], r1 = s_r[t + 1];
        float2 m0 = mel2[(size_t)t * 64 + lane];
        float2 m1 = mel2[(size_t)(t + 1) * 64 + lane];
        float d00 = k0 - fs0, d01 = k0 - fs1;
        float d10 = k1 - fs0, d11 = k1 - fs1;
        float g00 = __expf(-DELTA_C * d00 * d00) * r0;
        float g01 = __expf(-DELTA_C * d01 * d01) * r0;
        float g10 = __expf(-DELTA_C * d10 * d10) * r1;
        float g11 = __expf(-DELTA_C * d11 * d11) * r1;
        g0s += g00 + g10; g1s += g01 + g11;
        ax0 += g00 * m0.x + g10 * m1.x;  ay0 += g00 * m0.y + g10 * m1.y;
        ax1 += g01 * m0.x + g11 * m1.x;  ay1 += g01 * m0.y + g11 * m1.y;
    }
    for (; t < t_hi; t++) {
        float k = s_key[t], r = s_r[t];
        float2 m = mel2[(size_t)t * 64 + lane];
        float d0 = k - fs0, d1 = k - fs1;
        float ga = __expf(-DELTA_C * d0 * d0) * r;
        float gb = __expf(-DELTA_C * d1 * d1) * r;
        g0s += ga; g1s += gb;
        ax0 += ga * m.x; ay0 += ga * m.y;
        ax1 += gb * m.x; ay1 += gb * m.y;
    }

    float tm0 = (float)s_tm[s0];
    float tm1 = (float)s_tm[s0 + 1];
    float inv0 = tm0 / (g0s + EPS_C);
    float inv1 = tm1 / (g1s + EPS_C);
    float2 o0 = {ax0 * inv0, ay0 * inv0};
    float2 o1 = {ax1 * inv1, ay1 * inv1};
    ((float2*)(aligned + ((size_t)b * T1_ + s0) * F_))[lane] = o0;
    ((float2*)(aligned + ((size_t)b * T1_ + s0 + 1) * F_))[lane] = o1;
    if (lane == 0) {
        dur[(size_t)b * T1_ + s0]     = g0s * tm0;
        dur[(size_t)b * T1_ + s0 + 1] = g1s * tm1;
    }
}

extern "C" void kernel_launch(void* const* d_in, const int* in_sizes, int n_in,
                              void* d_out, int out_size, void* d_ws, size_t ws_size,
                              hipStream_t stream) {
    const float* mels      = (const float*)d_in[0];
    const float* alpha     = (const float*)d_in[1];
    const int*   mel_mask  = (const int*)d_in[2];
    const int*   text_mask = (const int*)d_in[3];

    float* out     = (float*)d_out;
    float* aligned = out;                                   // B*T1*F
    float* dur     = out + (size_t)B_ * T1_ * F_;           // B*T1
    float* imv     = dur + (size_t)B_ * T1_;                // B*T2

    float2* pa = (float2*)d_ws;                             // B*T2 float2 = 256 KB

    dim3 blk(256);
    actprop_kernel<<<(B_ * T2_) / 4, blk, 0, stream>>>(mels, alpha, mel_mask, pa);
    pool_kernel   <<<B_ * 64,        blk, 0, stream>>>(mels, pa, mel_mask, text_mask, imv, aligned, dur);
}